// Round 2
// baseline (617.191 us; speedup 1.0000x reference)
//
#include <hip/hip_runtime.h>

#define NVEC 131072          // 32*64*64 vectors
#define KC 512               // codebook size
#define DD 64                // code dim
#define QOUT_OFF 1
#define PERP_OFF 8388609
#define ENC_OFF  8388610     // NOTE: byte offset % 16 == 8 -> float2 max width there

// ws layout: [0,2048) wnorm (512 f32) | [2048,4096) hist (512 u32) | [4096,12288) wave partials (2048 f32)

// ---------------- init: codebook norms + zero hist ----------------
__global__ void vq_init(const float* __restrict__ w, float* __restrict__ wnorm,
                        unsigned int* __restrict__ hist) {
    int k = threadIdx.x;  // 512 threads
    const float* wr = w + k * DD;
    float s = 0.f;
#pragma unroll
    for (int d = 0; d < DD; ++d) s = fmaf(wr[d], wr[d], s);
    wnorm[k] = s;
    hist[k] = 0u;
}

// ---------------- main: argmin + quantize + loss + one-hot ----------------
__global__ __launch_bounds__(256, 2) void vq_main(
    const float* __restrict__ x, const float* __restrict__ w,
    const float* __restrict__ wnorm, float* __restrict__ out,
    unsigned int* __restrict__ hist, float* __restrict__ partials) {
    const int tid = threadIdx.x;
    const int n  = blockIdx.x * 256 + tid;
    const int b  = n >> 12;          // image index (4096 pixels/image)
    const int hw = n & 4095;

    // x vector: stride-4096 per d, lane-coalesced (256B per wave-instr)
    const float* xp = x + ((size_t)b << 18) + hw;
    float xv[DD];
#pragma unroll
    for (int d = 0; d < DD; ++d) xv[d] = xp[(size_t)d << 12];

    float xx0 = 0.f, xx1 = 0.f, xx2 = 0.f, xx3 = 0.f;
#pragma unroll
    for (int d = 0; d < DD; d += 4) {
        xx0 = fmaf(xv[d],   xv[d],   xx0);
        xx1 = fmaf(xv[d+1], xv[d+1], xx1);
        xx2 = fmaf(xv[d+2], xv[d+2], xx2);
        xx3 = fmaf(xv[d+3], xv[d+3], xx3);
    }
    const float xx = (xx0 + xx1) + (xx2 + xx3);

    // encodings zero-fill, INTERLEAVED with the k-loop so the 256 MB of
    // stores drain under the VALU phase (an up-front loop stalls on vmcnt).
    // Block region = 256 rows * 512 = 131072 floats = 65536 float2.
    // Each thread: 256 float2 stores, one every 2nd k iteration.
    const float2 z2 = make_float2(0.f, 0.f);
    float2* encb2 = (float2*)(out + ENC_OFF) + ((size_t)blockIdx.x << 16) + tid;

    // argmin over 512 codes; codebook rows are wave-uniform, L1/L2-hot
    float best = 3.402823466e38f;
    int bidx = 0;
#pragma unroll 4
    for (int k = 0; k < KC; ++k) {
        if ((k & 1) == 0) encb2[(size_t)(k >> 1) << 8] = z2;  // lanes consecutive: 512B/instr
        const float4* w4 = (const float4*)(w + (k << 6));
        float a0 = 0.f, a1 = 0.f, a2 = 0.f, a3 = 0.f;
#pragma unroll
        for (int i = 0; i < 16; ++i) {
            float4 wv = w4[i];
            int d = i * 4;
            a0 = fmaf(wv.x, xv[d],   a0);
            a1 = fmaf(wv.y, xv[d+1], a1);
            a2 = fmaf(wv.z, xv[d+2], a2);
            a3 = fmaf(wv.w, xv[d+3], a3);
        }
        float dot = (a0 + a1) + (a2 + a3);
        // reference rounding order: (||x||^2 + ||e||^2) - 2*x.e
        // fma(-2,dot,t) == t - 2*dot exactly (2*dot is exact)
        float s = fmaf(-2.0f, dot, xx + wnorm[k]);
        if (s < best) { best = s; bidx = k; }   // first-min tie rule == jnp.argmin
    }

    // histogram for perplexity (avg 256 hits/address, no hotspot expected)
    atomicAdd(&hist[bidx], 1u);

    // quantized gather (row 256B-aligned, L2-hot) + NCHW store + loss
    const float4* q4 = (const float4*)(w + (bidx << 6));
    float* qo = out + QOUT_OFF + ((size_t)b << 18) + hw;
    float ls0 = 0.f, ls1 = 0.f, ls2 = 0.f, ls3 = 0.f;
#pragma unroll
    for (int i = 0; i < 16; ++i) {
        float4 q = q4[i];
        int d = i * 4;
        float d0 = q.x - xv[d], d1 = q.y - xv[d+1];
        float d2 = q.z - xv[d+2], d3 = q.w - xv[d+3];
        ls0 = fmaf(d0, d0, ls0); ls1 = fmaf(d1, d1, ls1);
        ls2 = fmaf(d2, d2, ls2); ls3 = fmaf(d3, d3, ls3);
        qo[(size_t)(d)   << 12] = q.x;
        qo[(size_t)(d+1) << 12] = q.y;
        qo[(size_t)(d+2) << 12] = q.z;
        qo[(size_t)(d+3) << 12] = q.w;
    }
    float ls = (ls0 + ls1) + (ls2 + ls3);
#pragma unroll
    for (int off = 32; off > 0; off >>= 1) ls += __shfl_down(ls, off);
    if ((tid & 63) == 0) partials[n >> 6] = ls;  // one slot per wave, no atomics

    // one-hot store; barrier orders it after this block's zero-fill
    __syncthreads();
    out[ENC_OFF + ((size_t)n << 9) + bidx] = 1.0f;
}

// ---------------- final: loss scale + perplexity ----------------
__global__ void vq_final(const unsigned int* __restrict__ hist,
                         const float* __restrict__ partials,
                         float* __restrict__ out) {
    __shared__ float rede[KC];
    __shared__ float redl[KC];
    int k = threadIdx.x;  // 512 threads
    float p = (float)hist[k] * (1.0f / (float)NVEC);  // exact: count / 2^17
    rede[k] = p * logf(p + 1e-10f);
    float l = 0.f;
#pragma unroll
    for (int i = 0; i < 4; ++i) l += partials[k * 4 + i];
    redl[k] = l;
    __syncthreads();
    for (int s = KC / 2; s > 0; s >>= 1) {
        if (k < s) { rede[k] += rede[k + s]; redl[k] += redl[k + s]; }
        __syncthreads();
    }
    if (k == 0) {
        out[PERP_OFF] = expf(-rede[0]);
        // loss = loss_q + 0.25*loss_e; both equal mean((q-x)^2) in fwd value
        out[0] = 1.25f * redl[0] * (1.0f / 8388608.0f);
    }
}

extern "C" void kernel_launch(void* const* d_in, const int* in_sizes, int n_in,
                              void* d_out, int out_size, void* d_ws, size_t ws_size,
                              hipStream_t stream) {
    const float* x = (const float*)d_in[0];
    const float* w = (const float*)d_in[1];
    float* out = (float*)d_out;

    float* wnorm       = (float*)d_ws;
    unsigned int* hist = (unsigned int*)((char*)d_ws + 2048);
    float* partials    = (float*)((char*)d_ws + 4096);   // 2048 floats

    vq_init<<<1, KC, 0, stream>>>(w, wnorm, hist);
    vq_main<<<NVEC / 256, 256, 0, stream>>>(x, w, wnorm, out, hist, partials);
    vq_final<<<1, KC, 0, stream>>>(hist, partials, out);
}

// Round 9
// 568.505 us; speedup vs baseline: 1.0856x; 1.0856x over previous
//
#include <hip/hip_runtime.h>

#define NVEC 131072          // 32*64*64 vectors
#define KC 512               // codebook size
#define DD 64                // code dim
#define HALF_N 65536         // NVEC/2 (V=2 register blocking)
#define QOUT_OFF 1
#define PERP_OFF 8388609
#define ENC_OFF  8388610     // byte offset % 16 == 8 -> float2 max width there
#define TILE_K 256           // codes per LDS tile (64 KB)

// ws: [0,2048) wnorm | [2048,4096) hist | [4096,8192) wave partials (1024 f32)

// ---------------- init: codebook norms + zero hist ----------------
__global__ void vq_init(const float* __restrict__ w, float* __restrict__ wnorm,
                        unsigned int* __restrict__ hist) {
    int k = threadIdx.x;  // 512 threads
    const float* wr = w + k * DD;
    float s = 0.f;
#pragma unroll
    for (int d = 0; d < DD; ++d) s = fmaf(wr[d], wr[d], s);
    wnorm[k] = s;
    hist[k] = 0u;
}

// ---------------- main: argmin + quantize + loss + one-hot ----------------
// V=2: each thread owns vectors n and n+65536; each LDS float4 feeds 8 FMAs.
// 256 blocks = 1 block/CU, 1 wave/SIMD; latency covered by 8 acc chains.
// launch_bounds(256,1): full 512-VGPR budget -> no occupancy-driven remat
// (round-2 failure: VGPR=56, x re-loaded from global per code, 355us).
__global__ __launch_bounds__(256, 1) void vq_main(
    const float* __restrict__ x, const float* __restrict__ w,
    const float* __restrict__ wnorm, float* __restrict__ out,
    unsigned int* __restrict__ hist, float* __restrict__ partials) {
    __shared__ float lw[TILE_K * DD];   // 64 KB codebook tile
    __shared__ float lnorm[KC];         // 2 KB norms

    const int tid = threadIdx.x;
    const int n0 = blockIdx.x * 256 + tid;       // < 65536
    const int n1 = n0 + HALF_N;
    const int b0 = n0 >> 12, hw = n0 & 4095;     // 65536 % 4096 == 0 -> same hw
    const int b1 = b0 + 16;

    // x vectors: stride-4096 per d, lane-coalesced (256B per wave-instr)
    const float* xp0 = x + ((size_t)b0 << 18) + hw;
    const float* xp1 = x + ((size_t)b1 << 18) + hw;
    float xv0[DD], xv1[DD];
#pragma unroll
    for (int d = 0; d < DD; ++d) xv0[d] = xp0[(size_t)d << 12];
#pragma unroll
    for (int d = 0; d < DD; ++d) xv1[d] = xp1[(size_t)d << 12];
    // Pin in VGPRs: SCALAR "+v" ties only (float4/tuple ties are rejected:
    // "tied indirect register inputs", round-8 compile error). Grouped 4/asm.
#pragma unroll
    for (int d = 0; d < DD; d += 4)
        asm volatile("" : "+v"(xv0[d]), "+v"(xv0[d+1]), "+v"(xv0[d+2]), "+v"(xv0[d+3]));
#pragma unroll
    for (int d = 0; d < DD; d += 4)
        asm volatile("" : "+v"(xv1[d]), "+v"(xv1[d+1]), "+v"(xv1[d+2]), "+v"(xv1[d+3]));

    float p0 = 0.f, p1 = 0.f, p2 = 0.f, p3 = 0.f;
    float q0 = 0.f, q1 = 0.f, q2 = 0.f, q3 = 0.f;
#pragma unroll
    for (int d = 0; d < DD; d += 4) {
        p0 = fmaf(xv0[d],   xv0[d],   p0);
        p1 = fmaf(xv0[d+1], xv0[d+1], p1);
        p2 = fmaf(xv0[d+2], xv0[d+2], p2);
        p3 = fmaf(xv0[d+3], xv0[d+3], p3);
        q0 = fmaf(xv1[d],   xv1[d],   q0);
        q1 = fmaf(xv1[d+1], xv1[d+1], q1);
        q2 = fmaf(xv1[d+2], xv1[d+2], q2);
        q3 = fmaf(xv1[d+3], xv1[d+3], q3);
    }
    const float xx0 = (p0 + p1) + (p2 + p3);
    const float xx1 = (q0 + q1) + (q2 + q3);

    lnorm[tid]       = wnorm[tid];
    lnorm[tid + 256] = wnorm[tid + 256];

    // encodings zero-fill interleaved with compute (512 float2/thread, one per
    // code iteration) so 256 MB of stores drain under the VALU phase.
    const float2 z2 = make_float2(0.f, 0.f);
    float2* e0 = (float2*)(out + ENC_OFF) + ((size_t)blockIdx.x << 16) + tid;
    float2* e1 = e0 + ((size_t)HALF_N << 8);   // +65536 rows * 256 float2

    float best0 = 3.402823466e38f, best1 = 3.402823466e38f;
    int bi0 = 0, bi1 = 0;

    for (int t = 0; t < 2; ++t) {
        const float4* wg = (const float4*)(w + (t << 14));
        float4* lw4 = (float4*)lw;
#pragma unroll 4
        for (int j = tid; j < TILE_K * DD / 4; j += 256) lw4[j] = wg[j];
        __syncthreads();

        for (int kk = 0; kk < TILE_K; ++kk) {
            const int k = (t << 8) + kk;
            if (t == 0) e0[(size_t)k << 8] = z2;          // all threads zero row k
            else        e1[(size_t)(k - 256) << 8] = z2;
            const float4* lrow = (const float4*)(lw + (kk << 6));
            float a0 = 0.f, a1 = 0.f, a2 = 0.f, a3 = 0.f;
            float c0 = 0.f, c1 = 0.f, c2 = 0.f, c3 = 0.f;
#pragma unroll
            for (int i = 0; i < 16; ++i) {
                const float4 wv = lrow[i];   // wave-uniform ds_read_b128 broadcast
                const int d = i * 4;
                a0 = fmaf(wv.x, xv0[d],   a0);
                a1 = fmaf(wv.y, xv0[d+1], a1);
                a2 = fmaf(wv.z, xv0[d+2], a2);
                a3 = fmaf(wv.w, xv0[d+3], a3);
                c0 = fmaf(wv.x, xv1[d],   c0);
                c1 = fmaf(wv.y, xv1[d+1], c1);
                c2 = fmaf(wv.z, xv1[d+2], c2);
                c3 = fmaf(wv.w, xv1[d+3], c3);
            }
            float dot0 = (a0 + a1) + (a2 + a3);
            float dot1 = (c0 + c1) + (c2 + c3);
            // reference rounding order: (||x||^2 + ||e||^2) - 2*x.e
            float s0 = fmaf(-2.0f, dot0, xx0 + lnorm[k]);
            float s1 = fmaf(-2.0f, dot1, xx1 + lnorm[k]);
            if (s0 < best0) { best0 = s0; bi0 = k; }  // first-min == jnp.argmin
            if (s1 < best1) { best1 = s1; bi1 = k; }
        }
        __syncthreads();
    }

    atomicAdd(&hist[bi0], 1u);
    atomicAdd(&hist[bi1], 1u);

    // quantized gather (rows 256B-aligned, L2-hot) + NCHW store + loss
    float ls0 = 0.f, ls1 = 0.f, ls2 = 0.f, ls3 = 0.f;
    {
        const float4* g = (const float4*)(w + (bi0 << 6));
        float* qo = out + QOUT_OFF + ((size_t)b0 << 18) + hw;
#pragma unroll
        for (int i = 0; i < 16; ++i) {
            float4 qv = g[i];
            const int d = i * 4;
            float d0 = qv.x - xv0[d], d1 = qv.y - xv0[d+1];
            float d2 = qv.z - xv0[d+2], d3 = qv.w - xv0[d+3];
            ls0 = fmaf(d0, d0, ls0); ls1 = fmaf(d1, d1, ls1);
            ls2 = fmaf(d2, d2, ls2); ls3 = fmaf(d3, d3, ls3);
            qo[(size_t)(d)     << 12] = qv.x;
            qo[(size_t)(d + 1) << 12] = qv.y;
            qo[(size_t)(d + 2) << 12] = qv.z;
            qo[(size_t)(d + 3) << 12] = qv.w;
        }
    }
    {
        const float4* g = (const float4*)(w + (bi1 << 6));
        float* qo = out + QOUT_OFF + ((size_t)b1 << 18) + hw;
#pragma unroll
        for (int i = 0; i < 16; ++i) {
            float4 qv = g[i];
            const int d = i * 4;
            float d0 = qv.x - xv1[d], d1 = qv.y - xv1[d+1];
            float d2 = qv.z - xv1[d+2], d3 = qv.w - xv1[d+3];
            ls0 = fmaf(d0, d0, ls0); ls1 = fmaf(d1, d1, ls1);
            ls2 = fmaf(d2, d2, ls2); ls3 = fmaf(d3, d3, ls3);
            qo[(size_t)(d)     << 12] = qv.x;
            qo[(size_t)(d + 1) << 12] = qv.y;
            qo[(size_t)(d + 2) << 12] = qv.z;
            qo[(size_t)(d + 3) << 12] = qv.w;
        }
    }
    float ls = (ls0 + ls1) + (ls2 + ls3);
#pragma unroll
    for (int off = 32; off > 0; off >>= 1) ls += __shfl_down(ls, off);
    if ((tid & 63) == 0) partials[n0 >> 6] = ls;  // 1024 wave slots, no atomics

    // one-hot; barrier orders after this block's zero-fill (vmcnt(0)+s_barrier)
    __syncthreads();
    out[ENC_OFF + ((size_t)n0 << 9) + bi0] = 1.0f;
    out[ENC_OFF + ((size_t)n1 << 9) + bi1] = 1.0f;
}

// ---------------- final: loss scale + perplexity ----------------
__global__ void vq_final(const unsigned int* __restrict__ hist,
                         const float* __restrict__ partials,
                         float* __restrict__ out) {
    __shared__ float rede[KC];
    __shared__ float redl[KC];
    int k = threadIdx.x;  // 512 threads
    float p = (float)hist[k] * (1.0f / (float)NVEC);  // exact: count / 2^17
    rede[k] = p * logf(p + 1e-10f);
    redl[k] = partials[k * 2] + partials[k * 2 + 1];
    __syncthreads();
    for (int s = KC / 2; s > 0; s >>= 1) {
        if (k < s) { rede[k] += rede[k + s]; redl[k] += redl[k + s]; }
        __syncthreads();
    }
    if (k == 0) {
        out[PERP_OFF] = expf(-rede[0]);
        // loss = loss_q + 0.25*loss_e; both equal mean((q-x)^2) in fwd value
        out[0] = 1.25f * redl[0] * (1.0f / 8388608.0f);
    }
}

extern "C" void kernel_launch(void* const* d_in, const int* in_sizes, int n_in,
                              void* d_out, int out_size, void* d_ws, size_t ws_size,
                              hipStream_t stream) {
    const float* x = (const float*)d_in[0];
    const float* w = (const float*)d_in[1];
    float* out = (float*)d_out;

    float* wnorm       = (float*)d_ws;
    unsigned int* hist = (unsigned int*)((char*)d_ws + 2048);
    float* partials    = (float*)((char*)d_ws + 4096);   // 1024 floats

    vq_init<<<1, KC, 0, stream>>>(w, wnorm, hist);
    vq_main<<<NVEC / 512, 256, 0, stream>>>(x, w, wnorm, out, hist, partials);
    vq_final<<<1, KC, 0, stream>>>(hist, partials, out);
}

// Round 10
// 460.824 us; speedup vs baseline: 1.3393x; 1.2337x over previous
//
#include <hip/hip_runtime.h>

#define NVEC 131072          // 32*64*64 vectors
#define KC 512               // codebook size
#define DD 64                // code dim
#define QOUT_OFF 1
#define PERP_OFF 8388609
#define ENC_OFF  8388610     // even -> float2-aligned
#define TK 64                // codes per pass
#define NPASS 8
#define MBLK 64              // vectors per block
#define NBLK 2048            // NVEC / MBLK

// ws: [0,2048) wnorm | [2048,4096) hist | [4096,36864) partials (8192 f32)

// ---- init: codebook norms (EXACT r9 chain order) + zero hist; 32x16 grid ----
__global__ void vq_init(const float* __restrict__ w, float* __restrict__ wnorm,
                        unsigned int* __restrict__ hist) {
    int k = blockIdx.x * 16 + threadIdx.x;   // 0..511
    const float4* wr = (const float4*)(w + k * DD);
    float4 v[16];
#pragma unroll
    for (int i = 0; i < 16; ++i) v[i] = wr[i];   // 16 independent loads in flight
    float s = 0.f;
#pragma unroll
    for (int i = 0; i < 16; ++i) {               // d-ascending single chain == r9
        s = fmaf(v[i].x, v[i].x, s);
        s = fmaf(v[i].y, v[i].y, s);
        s = fmaf(v[i].z, v[i].z, s);
        s = fmaf(v[i].w, v[i].w, s);
    }
    wnorm[k] = s;
    hist[k] = 0u;
}

// ---- main: GEMM-tiled argmin + quantize + loss + one-hot ----
// Block: 64 vectors x all 512 codes (8 passes of 64). Threads 256 = 16 mg x 16 kg.
// Thread tile: 4 m x 4 k, 4 accumulator chains per pair (d mod 4) == r9 rounding.
// x and w tiles TRANSPOSED in LDS -> all compute reads are ds_read_b128 with
// immediate offsets, conflict-free; no long-lived register arrays -> no spill.
__global__ __launch_bounds__(256, 2) void vq_main(
    const float* __restrict__ x, const float* __restrict__ w,
    const float* __restrict__ wnorm, float* __restrict__ out,
    unsigned int* __restrict__ hist, float* __restrict__ partials) {
    __shared__ float lxT[DD][MBLK];   // 16 KB  [d][m]
    __shared__ float lwT[DD][TK];     // 16 KB  [d][k]
    __shared__ float lnorm[KC];       // 2 KB
    __shared__ int   sbid[MBLK];

    const int tid = threadIdx.x;
    const int m_ = tid & 63, qd = tid >> 6;    // staging/epilogue map
    const int kg = tid & 15, mg = tid >> 4;    // compute map

    const int n_base = blockIdx.x * MBLK;

    // stage x-tile transposed: thread (m_, qd) loads d = qd*16..+15, writes [d][m_]
    {
        const int n = n_base + m_;
        const float* xp = x + ((size_t)(n >> 12) << 18) + (n & 4095);
#pragma unroll
        for (int dd = 0; dd < 16; ++dd) {
            int d = qd * 16 + dd;
            lxT[d][m_] = xp[(size_t)d << 12];   // global coalesced, LDS write conflict-free
        }
    }
    lnorm[tid] = wnorm[tid];
    lnorm[tid + 256] = wnorm[tid + 256];
    __syncthreads();

    // per-thread ||x||^2 for its 4 m's: 4 chains by d mod 4 (== r9 order)
    float xxc[4][4];
#pragma unroll
    for (int j = 0; j < 4; ++j)
#pragma unroll
        for (int c = 0; c < 4; ++c) xxc[j][c] = 0.f;
#pragma unroll
    for (int dc = 0; dc < 16; ++dc)
#pragma unroll
        for (int c = 0; c < 4; ++c) {
            float4 xv = *(const float4*)&lxT[dc * 4 + c][mg * 4];
            xxc[0][c] = fmaf(xv.x, xv.x, xxc[0][c]);
            xxc[1][c] = fmaf(xv.y, xv.y, xxc[1][c]);
            xxc[2][c] = fmaf(xv.z, xv.z, xxc[2][c]);
            xxc[3][c] = fmaf(xv.w, xv.w, xxc[3][c]);
        }
    float xx[4];
#pragma unroll
    for (int j = 0; j < 4; ++j)
        xx[j] = (xxc[j][0] + xxc[j][1]) + (xxc[j][2] + xxc[j][3]);

    // encodings zero-fill: 64 float2/thread interleaved into the 128 d-chunks
    const float2 z2 = make_float2(0.f, 0.f);
    float2* encb = (float2*)(out + ENC_OFF) + ((size_t)blockIdx.x << 14) + tid;

    float best[4] = {3.4e38f, 3.4e38f, 3.4e38f, 3.4e38f};
    int bid[4] = {0, 0, 0, 0};

    for (int p = 0; p < NPASS; ++p) {
        // stage w-tile (codes p*64..+63) transposed; global float4 coalesced
#pragma unroll
        for (int r = 0; r < 4; ++r) {
            int j = r * 256 + tid;                    // 0..1023
            int kk = j >> 4, dc = j & 15;
            float4 wv = ((const float4*)w)[(p << 10) + j];
            lwT[dc * 4 + 0][kk] = wv.x;
            lwT[dc * 4 + 1][kk] = wv.y;
            lwT[dc * 4 + 2][kk] = wv.z;
            lwT[dc * 4 + 3][kk] = wv.w;
        }
        __syncthreads();

        float a[4][4][4];   // [j][i][chain]  all indices compile-time
#pragma unroll
        for (int j = 0; j < 4; ++j)
#pragma unroll
            for (int i = 0; i < 4; ++i)
#pragma unroll
                for (int c = 0; c < 4; ++c) a[j][i][c] = 0.f;

#pragma unroll
        for (int dc = 0; dc < 16; ++dc) {
            if ((dc & 1) == 0) encb[(size_t)(p * 8 + (dc >> 1)) << 8] = z2;
            float4 xf[4], wf[4];
#pragma unroll
            for (int c = 0; c < 4; ++c) {
                xf[c] = *(const float4*)&lxT[dc * 4 + c][mg * 4];  // 4 addr/wave, distinct banks
                wf[c] = *(const float4*)&lwT[dc * 4 + c][kg * 4];  // 2-way = free
            }
#pragma unroll
            for (int c = 0; c < 4; ++c) {
#define VQROW(j, xcomp)                                        \
                a[j][0][c] = fmaf(xcomp, wf[c].x, a[j][0][c]); \
                a[j][1][c] = fmaf(xcomp, wf[c].y, a[j][1][c]); \
                a[j][2][c] = fmaf(xcomp, wf[c].z, a[j][2][c]); \
                a[j][3][c] = fmaf(xcomp, wf[c].w, a[j][3][c]);
                VQROW(0, xf[c].x) VQROW(1, xf[c].y) VQROW(2, xf[c].z) VQROW(3, xf[c].w)
#undef VQROW
            }
        }

        // fold 16 scores; k ascending (i asc, p asc) -> first-min == jnp.argmin
        float4 ln4 = *(const float4*)&lnorm[p * 64 + kg * 4];
        float lnv[4] = {ln4.x, ln4.y, ln4.z, ln4.w};
#pragma unroll
        for (int j = 0; j < 4; ++j)
#pragma unroll
            for (int i = 0; i < 4; ++i) {
                float dot = (a[j][i][0] + a[j][i][1]) + (a[j][i][2] + a[j][i][3]);
                float s = fmaf(-2.0f, dot, xx[j] + lnv[i]);   // == r9 rounding
                if (s < best[j]) { best[j] = s; bid[j] = p * 64 + kg * 4 + i; }
            }
        __syncthreads();   // before next pass overwrites lwT
    }

    // cross-lane argmin over the 16 kg lanes (lane bits 0-3), ties -> lower k
#pragma unroll
    for (int mask = 1; mask <= 8; mask <<= 1)
#pragma unroll
        for (int j = 0; j < 4; ++j) {
            float ov = __shfl_xor(best[j], mask);
            int oi = __shfl_xor(bid[j], mask);
            if (ov < best[j] || (ov == best[j] && oi < bid[j])) { best[j] = ov; bid[j] = oi; }
        }
    if (kg == 0) {
#pragma unroll
        for (int j = 0; j < 4; ++j) sbid[mg * 4 + j] = bid[j];
    }
    __syncthreads();

    // epilogue: thread (m_, qd) handles 16 d's of vector m_
    const int n = n_base + m_;
    const int bidx = sbid[m_];
    if (tid < 64) atomicAdd(&hist[bidx], 1u);
    float* qo = out + QOUT_OFF + ((size_t)(n >> 12) << 18) + (n & 4095);
    const float4* wrow = (const float4*)(w + (bidx << 6)) + (qd << 2);
    float ls0 = 0.f, ls1 = 0.f, ls2 = 0.f, ls3 = 0.f;
#pragma unroll
    for (int i = 0; i < 4; ++i) {
        float4 qv = wrow[i];
        int d = qd * 16 + i * 4;
        float d0 = qv.x - lxT[d][m_],     d1 = qv.y - lxT[d + 1][m_];
        float d2 = qv.z - lxT[d + 2][m_], d3 = qv.w - lxT[d + 3][m_];
        ls0 = fmaf(d0, d0, ls0); ls1 = fmaf(d1, d1, ls1);
        ls2 = fmaf(d2, d2, ls2); ls3 = fmaf(d3, d3, ls3);
        qo[(size_t)(d) << 12]     = qv.x;
        qo[(size_t)(d + 1) << 12] = qv.y;
        qo[(size_t)(d + 2) << 12] = qv.z;
        qo[(size_t)(d + 3) << 12] = qv.w;
    }
    float ls = (ls0 + ls1) + (ls2 + ls3);
#pragma unroll
    for (int off = 32; off > 0; off >>= 1) ls += __shfl_down(ls, off);
    if ((tid & 63) == 0) partials[blockIdx.x * 4 + (tid >> 6)] = ls;

    // one-hot after barrier (all this block's enc-zero stores drained)
    __syncthreads();
    if (tid < 64) out[ENC_OFF + ((size_t)n << 9) + bidx] = 1.0f;
}

// ---- final: loss scale + perplexity ----
__global__ void vq_final(const unsigned int* __restrict__ hist,
                         const float* __restrict__ partials,
                         float* __restrict__ out) {
    __shared__ float rede[KC];
    __shared__ float redl[KC];
    int k = threadIdx.x;  // 512
    float p = (float)hist[k] * (1.0f / (float)NVEC);
    rede[k] = p * logf(p + 1e-10f);
    float l = 0.f;
#pragma unroll
    for (int i = 0; i < 16; ++i) l += partials[k * 16 + i];
    redl[k] = l;
    __syncthreads();
    for (int s = KC / 2; s > 0; s >>= 1) {
        if (k < s) { rede[k] += rede[k + s]; redl[k] += redl[k + s]; }
        __syncthreads();
    }
    if (k == 0) {
        out[PERP_OFF] = expf(-rede[0]);
        out[0] = 1.25f * redl[0] * (1.0f / 8388608.0f);
    }
}

extern "C" void kernel_launch(void* const* d_in, const int* in_sizes, int n_in,
                              void* d_out, int out_size, void* d_ws, size_t ws_size,
                              hipStream_t stream) {
    const float* x = (const float*)d_in[0];
    const float* w = (const float*)d_in[1];
    float* out = (float*)d_out;

    float* wnorm       = (float*)d_ws;
    unsigned int* hist = (unsigned int*)((char*)d_ws + 2048);
    float* partials    = (float*)((char*)d_ws + 4096);   // 8192 floats

    vq_init<<<32, 16, 0, stream>>>(w, wnorm, hist);
    vq_main<<<NBLK, 256, 0, stream>>>(x, w, wnorm, out, hist, partials);
    vq_final<<<1, KC, 0, stream>>>(hist, partials, out);
}

// Round 11
// 422.553 us; speedup vs baseline: 1.4606x; 1.0906x over previous
//
#include <hip/hip_runtime.h>

#define NVEC 131072          // 32*64*64 vectors
#define KC 512               // codebook size
#define DD 64                // code dim
#define QOUT_OFF 1
#define PERP_OFF 8388609
#define ENC_OFF  8388610     // even -> float2-aligned
#define TK 64                // codes per pass
#define NPASS 8
#define MBLK 64              // vectors per block
#define NBLK 2048            // NVEC / MBLK

// ws: [0,2048) wnorm | [2048,4096) hist | [4096,36864) partials (8192 f32)

// ---- init: codebook norms (EXACT r9/r10 chain order) + zero hist ----
__global__ void vq_init(const float* __restrict__ w, float* __restrict__ wnorm,
                        unsigned int* __restrict__ hist) {
    int k = blockIdx.x * 256 + threadIdx.x;   // 0..511
    const float4* wr = (const float4*)(w + k * DD);
    float4 v[16];
#pragma unroll
    for (int i = 0; i < 16; ++i) v[i] = wr[i];   // loads batched in flight
    float s = 0.f;
#pragma unroll
    for (int i = 0; i < 16; ++i) {               // d-ascending single chain
        s = fmaf(v[i].x, v[i].x, s);
        s = fmaf(v[i].y, v[i].y, s);
        s = fmaf(v[i].z, v[i].z, s);
        s = fmaf(v[i].w, v[i].w, s);
    }
    wnorm[k] = s;
    hist[k] = 0u;
}

// ---- main: GEMM-tiled argmin + quantize + loss + one-hot ----
// x-tile transposed [d][m] (writes 2-way-free, reads broadcast-free).
// w-tile code-major float4 with chunk-XOR swizzle lw4[kk][dc ^ (kk>>2)]:
//   staging = one b128 write (8 bank-quads, structurally optimal — fixes r10's
//   16-way scalar-write conflict, 3.15e7 cycles), read = 8 quads x 2 addrs.
__global__ __launch_bounds__(256, 2) void vq_main(
    const float* __restrict__ x, const float* __restrict__ w,
    const float* __restrict__ wnorm, float* __restrict__ out,
    unsigned int* __restrict__ hist, float* __restrict__ partials) {
    __shared__ float  lxT[DD][MBLK];   // 16 KB  [d][m]
    __shared__ float4 lw4[TK][16];     // 16 KB  [k][d-chunk swizzled]
    __shared__ float  lnorm[KC];       // 2 KB
    __shared__ int    sbid[MBLK];

    const int tid = threadIdx.x;
    const int m_ = tid & 63, qd = tid >> 6;    // staging/epilogue map
    const int kg = tid & 15, mg = tid >> 4;    // compute map

    const int n_base = blockIdx.x * MBLK;

    // stage x-tile transposed: thread (m_, qd) loads d = qd*16..+15
    {
        const int n = n_base + m_;
        const float* xp = x + ((size_t)(n >> 12) << 18) + (n & 4095);
#pragma unroll
        for (int dd = 0; dd < 16; ++dd) {
            int d = qd * 16 + dd;
            lxT[d][m_] = xp[(size_t)d << 12];   // global coalesced, LDS 2-way free
        }
    }
    lnorm[tid] = wnorm[tid];
    lnorm[tid + 256] = wnorm[tid + 256];
    __syncthreads();

    // per-thread ||x||^2 for its 4 m's: 4 chains by d mod 4 (== r9/r10 order)
    float xxc[4][4];
#pragma unroll
    for (int j = 0; j < 4; ++j)
#pragma unroll
        for (int c = 0; c < 4; ++c) xxc[j][c] = 0.f;
#pragma unroll
    for (int dc = 0; dc < 16; ++dc)
#pragma unroll
        for (int c = 0; c < 4; ++c) {
            float4 xv = *(const float4*)&lxT[dc * 4 + c][mg * 4];
            xxc[0][c] = fmaf(xv.x, xv.x, xxc[0][c]);
            xxc[1][c] = fmaf(xv.y, xv.y, xxc[1][c]);
            xxc[2][c] = fmaf(xv.z, xv.z, xxc[2][c]);
            xxc[3][c] = fmaf(xv.w, xv.w, xxc[3][c]);
        }
    float xx[4];
#pragma unroll
    for (int j = 0; j < 4; ++j)
        xx[j] = (xxc[j][0] + xxc[j][1]) + (xxc[j][2] + xxc[j][3]);

    // encodings zero-fill: 64 float2/thread interleaved across the passes
    const float2 z2 = make_float2(0.f, 0.f);
    float2* encb = (float2*)(out + ENC_OFF) + ((size_t)blockIdx.x << 14) + tid;

    float best[4] = {3.4e38f, 3.4e38f, 3.4e38f, 3.4e38f};
    int bid[4] = {0, 0, 0, 0};

    for (int p = 0; p < NPASS; ++p) {
        // stage w-tile: coalesced global float4 -> single swizzled b128 write
#pragma unroll
        for (int r = 0; r < 4; ++r) {
            int j = r * 256 + tid;                    // 0..1023
            int kk = j >> 4, dc = j & 15;
            lw4[kk][dc ^ (kk >> 2)] = ((const float4*)w)[(p << 10) + j];
        }
        __syncthreads();

        float a[4][4][4];   // [j=m][i=k][chain=d%4], all indices compile-time
#pragma unroll
        for (int j = 0; j < 4; ++j)
#pragma unroll
            for (int i = 0; i < 4; ++i)
#pragma unroll
                for (int c = 0; c < 4; ++c) a[j][i][c] = 0.f;

#pragma unroll
        for (int dc = 0; dc < 16; ++dc) {
            if ((dc & 1) == 0) encb[(size_t)(p * 8 + (dc >> 1)) << 8] = z2;
            float4 xf[4], wq[4];
#pragma unroll
            for (int c = 0; c < 4; ++c)
                xf[c] = *(const float4*)&lxT[dc * 4 + c][mg * 4];  // 4 quads, bcast
            const int ch = dc ^ kg;                                 // swizzled chunk
#pragma unroll
            for (int i = 0; i < 4; ++i) wq[i] = lw4[kg * 4 + i][ch]; // 8 quads x 2
#pragma unroll
            for (int i = 0; i < 4; ++i) {
                const float4 wv = wq[i];
                a[0][i][0] = fmaf(xf[0].x, wv.x, a[0][i][0]);
                a[1][i][0] = fmaf(xf[0].y, wv.x, a[1][i][0]);
                a[2][i][0] = fmaf(xf[0].z, wv.x, a[2][i][0]);
                a[3][i][0] = fmaf(xf[0].w, wv.x, a[3][i][0]);
                a[0][i][1] = fmaf(xf[1].x, wv.y, a[0][i][1]);
                a[1][i][1] = fmaf(xf[1].y, wv.y, a[1][i][1]);
                a[2][i][1] = fmaf(xf[1].z, wv.y, a[2][i][1]);
                a[3][i][1] = fmaf(xf[1].w, wv.y, a[3][i][1]);
                a[0][i][2] = fmaf(xf[2].x, wv.z, a[0][i][2]);
                a[1][i][2] = fmaf(xf[2].y, wv.z, a[1][i][2]);
                a[2][i][2] = fmaf(xf[2].z, wv.z, a[2][i][2]);
                a[3][i][2] = fmaf(xf[2].w, wv.z, a[3][i][2]);
                a[0][i][3] = fmaf(xf[3].x, wv.w, a[0][i][3]);
                a[1][i][3] = fmaf(xf[3].y, wv.w, a[1][i][3]);
                a[2][i][3] = fmaf(xf[3].z, wv.w, a[2][i][3]);
                a[3][i][3] = fmaf(xf[3].w, wv.w, a[3][i][3]);
            }
        }

        // fold 16 scores; k ascending (i asc, p asc) -> first-min == jnp.argmin
        float4 ln4 = *(const float4*)&lnorm[p * 64 + kg * 4];
        float lnv[4] = {ln4.x, ln4.y, ln4.z, ln4.w};
#pragma unroll
        for (int j = 0; j < 4; ++j)
#pragma unroll
            for (int i = 0; i < 4; ++i) {
                float dot = (a[j][i][0] + a[j][i][1]) + (a[j][i][2] + a[j][i][3]);
                float s = fmaf(-2.0f, dot, xx[j] + lnv[i]);   // == r9/r10 rounding
                if (s < best[j]) { best[j] = s; bid[j] = p * 64 + kg * 4 + i; }
            }
        __syncthreads();   // before next pass overwrites lw4
    }

    // cross-lane argmin over the 16 kg lanes (lane bits 0-3), ties -> lower k
#pragma unroll
    for (int mask = 1; mask <= 8; mask <<= 1)
#pragma unroll
        for (int j = 0; j < 4; ++j) {
            float ov = __shfl_xor(best[j], mask);
            int oi = __shfl_xor(bid[j], mask);
            if (ov < best[j] || (ov == best[j] && oi < bid[j])) { best[j] = ov; bid[j] = oi; }
        }
    if (kg == 0) {
#pragma unroll
        for (int j = 0; j < 4; ++j) sbid[mg * 4 + j] = bid[j];
    }
    __syncthreads();

    // epilogue: thread (m_, qd) handles 16 d's of vector m_
    const int n = n_base + m_;
    const int bidx = sbid[m_];
    if (tid < 64) atomicAdd(&hist[bidx], 1u);
    float* qo = out + QOUT_OFF + ((size_t)(n >> 12) << 18) + (n & 4095);
    const float4* wrow = (const float4*)(w + (bidx << 6)) + (qd << 2);
    float ls0 = 0.f, ls1 = 0.f, ls2 = 0.f, ls3 = 0.f;
#pragma unroll
    for (int i = 0; i < 4; ++i) {
        float4 qv = wrow[i];
        int d = qd * 16 + i * 4;
        float d0 = qv.x - lxT[d][m_],     d1 = qv.y - lxT[d + 1][m_];
        float d2 = qv.z - lxT[d + 2][m_], d3 = qv.w - lxT[d + 3][m_];
        ls0 = fmaf(d0, d0, ls0); ls1 = fmaf(d1, d1, ls1);
        ls2 = fmaf(d2, d2, ls2); ls3 = fmaf(d3, d3, ls3);
        qo[(size_t)(d) << 12]     = qv.x;
        qo[(size_t)(d + 1) << 12] = qv.y;
        qo[(size_t)(d + 2) << 12] = qv.z;
        qo[(size_t)(d + 3) << 12] = qv.w;
    }
    float ls = (ls0 + ls1) + (ls2 + ls3);
#pragma unroll
    for (int off = 32; off > 0; off >>= 1) ls += __shfl_down(ls, off);
    if ((tid & 63) == 0) partials[blockIdx.x * 4 + (tid >> 6)] = ls;

    // one-hot after barrier (all this block's enc-zero stores drained)
    __syncthreads();
    if (tid < 64) out[ENC_OFF + ((size_t)n << 9) + bidx] = 1.0f;
}

// ---- final: loss scale + perplexity ----
__global__ void vq_final(const unsigned int* __restrict__ hist,
                         const float* __restrict__ partials,
                         float* __restrict__ out) {
    __shared__ float rede[KC];
    __shared__ float redl[KC];
    int k = threadIdx.x;  // 512
    float p = (float)hist[k] * (1.0f / (float)NVEC);
    rede[k] = p * logf(p + 1e-10f);
    float l = 0.f;
#pragma unroll
    for (int i = 0; i < 16; ++i) l += partials[k * 16 + i];
    redl[k] = l;
    __syncthreads();
    for (int s = KC / 2; s > 0; s >>= 1) {
        if (k < s) { rede[k] += rede[k + s]; redl[k] += redl[k + s]; }
        __syncthreads();
    }
    if (k == 0) {
        out[PERP_OFF] = expf(-rede[0]);
        out[0] = 1.25f * redl[0] * (1.0f / 8388608.0f);
    }
}

extern "C" void kernel_launch(void* const* d_in, const int* in_sizes, int n_in,
                              void* d_out, int out_size, void* d_ws, size_t ws_size,
                              hipStream_t stream) {
    const float* x = (const float*)d_in[0];
    const float* w = (const float*)d_in[1];
    float* out = (float*)d_out;

    float* wnorm       = (float*)d_ws;
    unsigned int* hist = (unsigned int*)((char*)d_ws + 2048);
    float* partials    = (float*)((char*)d_ws + 4096);   // 8192 floats

    vq_init<<<2, 256, 0, stream>>>(w, wnorm, hist);
    vq_main<<<NBLK, 256, 0, stream>>>(x, w, wnorm, out, hist, partials);
    vq_final<<<1, KC, 0, stream>>>(hist, partials, out);
}